// Round 8
// baseline (625.823 us; speedup 1.0000x reference)
//
#include <hip/hip_runtime.h>

typedef unsigned short u16;
typedef short short8 __attribute__((ext_vector_type(8)));
typedef u16 ush8 __attribute__((ext_vector_type(8)));
typedef __bf16 bf16x8 __attribute__((ext_vector_type(8)));
typedef float f32x4 __attribute__((ext_vector_type(4)));

#define NB 32
#define CDIM 384
#define NSP 2304
#define QCH 1152

__device__ __forceinline__ float b2f(u16 u) {
    union { unsigned i; float f; } v; v.i = ((unsigned)u) << 16; return v.f;
}
__device__ __forceinline__ u16 f2b(float f) {
    union { float f; unsigned i; } v; v.f = f;
    unsigned r = v.i + 0x7FFFu + ((v.i >> 16) & 1u);
    return (u16)(r >> 16);
}

// ---------------- K0: convert f32 weights to bf16 ----------
__global__ __launch_bounds__(256) void k_prep(const float* __restrict__ wqkv,
                                              const float* __restrict__ wproj,
                                              u16* __restrict__ wqkv_bf,
                                              u16* __restrict__ wproj_bf) {
    int i = blockIdx.x * 256 + threadIdx.x;
    if (i < QCH * CDIM) wqkv_bf[i] = f2b(wqkv[i]);
    if (i < CDIM * CDIM) wproj_bf[i] = f2b(wproj[i]);
}

// ---------------- K1: channel LayerNorm, single-pass register-resident, vectorized out ------
__global__ __launch_bounds__(256) void k_ln(const float* __restrict__ x,
                                            const float* __restrict__ lnw,
                                            const float* __restrict__ lnb,
                                            u16* __restrict__ xnt) {
    __shared__ float s_sum[4][64], s_sq[4][64], s_mu[64], s_rs[64];
    __shared__ u16 s_tile[64][392];   // 784B row stride: 16B aligned
    int b = blockIdx.y, n0 = blockIdx.x * 64;
    int tid = threadIdx.x, c4 = tid >> 6, nl = tid & 63;
    int cbase = c4 * 96;
    const float* xb = x + (size_t)b * CDIM * NSP + (size_t)cbase * NSP + n0 + nl;
    float v[96];
    float sum = 0.f, sq = 0.f;
#pragma unroll
    for (int j = 0; j < 96; j++) {
        v[j] = xb[(size_t)j * NSP];
        sum += v[j]; sq += v[j] * v[j];
    }
    s_sum[c4][nl] = sum; s_sq[c4][nl] = sq;
    __syncthreads();
    if (tid < 64) {
        float s = s_sum[0][tid] + s_sum[1][tid] + s_sum[2][tid] + s_sum[3][tid];
        float q = s_sq[0][tid] + s_sq[1][tid] + s_sq[2][tid] + s_sq[3][tid];
        float mu = s * (1.f / CDIM);
        float var = q * (1.f / CDIM) - mu * mu;
        s_mu[tid] = mu; s_rs[tid] = rsqrtf(var + 1e-5f);
    }
    __syncthreads();
    float mu = s_mu[nl], rs = s_rs[nl];
#pragma unroll
    for (int j = 0; j < 96; j++) {
        int c = cbase + j;
        s_tile[nl][c] = f2b((v[j] - mu) * rs * lnw[c] + lnb[c]);
    }
    __syncthreads();
    u16* o = xnt + ((size_t)b * NSP + n0) * CDIM;
    for (int i = tid; i < 64 * 48; i += 256) {
        int row = i / 48, c8 = i % 48;
        *(short8*)(o + row * CDIM + c8 * 8) = *(const short8*)(&s_tile[row][c8 * 8]);
    }
}

// ---------------- K2/K9: GEMM  C[b][m][n] = sum_k A[m][k] * Bt[b][n][k] ----------------
__global__ __launch_bounds__(256) void k_gemm(const u16* __restrict__ A,
                                              const u16* __restrict__ Bt,
                                              void* __restrict__ Cmat, int M, int f32out) {
    __shared__ u16 As[128][40], Bs[128][40];
    int tid = threadIdx.x;
    int bxn = blockIdx.x, bym = blockIdx.y, bz = blockIdx.z;
    int wave = tid >> 6, lane = tid & 63, wr = wave >> 1, wc = wave & 1;
    int lr = lane & 15, lk = lane >> 4;
    f32x4 acc[4][4];
#pragma unroll
    for (int m = 0; m < 4; m++)
#pragma unroll
        for (int n = 0; n < 4; n++) acc[m][n] = (f32x4){0.f, 0.f, 0.f, 0.f};
    int rs = tid >> 2, ks = (tid & 3) * 8;
    const u16* Ap0 = A + (size_t)(bym * 128 + rs) * 384 + ks;
    const u16* Ap1 = Ap0 + (size_t)64 * 384;
    const u16* Bp0 = Bt + ((size_t)bz * NSP + bxn * 128 + rs) * 384 + ks;
    const u16* Bp1 = Bp0 + (size_t)64 * 384;
    for (int k0 = 0; k0 < 384; k0 += 32) {
        *(short8*)(&As[rs][ks])      = *(const short8*)(Ap0 + k0);
        *(short8*)(&As[rs + 64][ks]) = *(const short8*)(Ap1 + k0);
        *(short8*)(&Bs[rs][ks])      = *(const short8*)(Bp0 + k0);
        *(short8*)(&Bs[rs + 64][ks]) = *(const short8*)(Bp1 + k0);
        __syncthreads();
        short8 af[4], bfr[4];
#pragma unroll
        for (int m = 0; m < 4; m++) af[m] = *(const short8*)(&As[wr * 64 + m * 16 + lr][lk * 8]);
#pragma unroll
        for (int n = 0; n < 4; n++) bfr[n] = *(const short8*)(&Bs[wc * 64 + n * 16 + lr][lk * 8]);
#pragma unroll
        for (int m = 0; m < 4; m++)
#pragma unroll
            for (int n = 0; n < 4; n++)
                acc[m][n] = __builtin_amdgcn_mfma_f32_16x16x32_bf16(
                    __builtin_bit_cast(bf16x8, af[m]), __builtin_bit_cast(bf16x8, bfr[n]),
                    acc[m][n], 0, 0, 0);
        __syncthreads();
    }
#pragma unroll
    for (int m = 0; m < 4; m++)
#pragma unroll
        for (int n = 0; n < 4; n++) {
            int row = bym * 128 + wr * 64 + m * 16 + lk * 4;
            int col = bxn * 128 + wc * 64 + n * 16 + lr;
            if (f32out) {
                float* cp = (float*)Cmat + ((size_t)bz * M + row) * NSP + col;
#pragma unroll
                for (int r = 0; r < 4; r++) cp[(size_t)r * NSP] = acc[m][n][r];
            } else {
                u16* cp = (u16*)Cmat + ((size_t)bz * M + row) * NSP + col;
#pragma unroll
                for (int r = 0; r < 4; r++) cp[(size_t)r * NSP] = f2b(acc[m][n][r]);
            }
        }
}

// ---------------- K3: 3x3 depthwise, NON-in-place (no barrier on datapath) ----------------
// Block: 192 threads = 4 planes x 48 rows; reads src, writes dst. Compiler pipelines freely.
__global__ __launch_bounds__(192) void k_dw3(const u16* __restrict__ src_qkv,
                                             u16* __restrict__ dst_qkv,
                                             const float* __restrict__ wdw,
                                             float* __restrict__ sumsq) {
    __shared__ float s_part[192];
    int bx = blockIdx.x, b = blockIdx.y, tid = threadIdx.x;
    int p = tid / 48, y = tid % 48;
    int ch = bx * 4 + p;
    const u16* plane = src_qkv + ((size_t)b * QCH + ch) * NSP;
    u16* oplane = dst_qkv + ((size_t)b * QCH + ch) * NSP;
    ush8 r0[6], r1[6], r2[6];
#pragma unroll
    for (int o = 0; o < 6; o++) {
        r1[o] = *(const ush8*)(plane + y * 48 + o * 8);
        if (y > 0)  r0[o] = *(const ush8*)(plane + (y - 1) * 48 + o * 8); else r0[o] = 0;
        if (y < 47) r2[o] = *(const ush8*)(plane + (y + 1) * 48 + o * 8); else r2[o] = 0;
    }
    float w[9];
#pragma unroll
    for (int i = 0; i < 9; i++) w[i] = wdw[ch * 9 + i];
    float ss = 0.f;
#pragma unroll
    for (int g = 0; g < 6; g++) {
        float a0[10], a1[10], a2[10];
#pragma unroll
        for (int j = 0; j < 10; j++) {
            int xi = g * 8 - 1 + j;
            if (xi < 0 || xi >= 48) { a0[j] = 0.f; a1[j] = 0.f; a2[j] = 0.f; }
            else {
                a0[j] = b2f(r0[xi >> 3][xi & 7]);
                a1[j] = b2f(r1[xi >> 3][xi & 7]);
                a2[j] = b2f(r2[xi >> 3][xi & 7]);
            }
        }
        union { u16 u[8]; short8 v; } pk;
#pragma unroll
        for (int x = 0; x < 8; x++) {
            float o = a0[x] * w[0] + a0[x + 1] * w[1] + a0[x + 2] * w[2]
                    + a1[x] * w[3] + a1[x + 1] * w[4] + a1[x + 2] * w[5]
                    + a2[x] * w[6] + a2[x + 1] * w[7] + a2[x + 2] * w[8];
            ss += o * o;
            pk.u[x] = f2b(o);
        }
        *(short8*)(oplane + y * 48 + g * 8) = pk.v;
    }
    s_part[tid] = ss;
    __syncthreads();
    if (bx < 192 && tid < 4) {
        float s = 0.f;
        for (int i = 0; i < 48; i++) s += s_part[tid * 48 + i];
        sumsq[b * 768 + bx * 4 + tid] = s;
    }
}

// ---------------- K4: 1/max(sqrt(ss),1e-12) ----------------
__global__ void k_rnorm(const float* __restrict__ ss, float* __restrict__ rn) {
    int i = blockIdx.x * 256 + threadIdx.x;
    if (i < NB * 768) rn[i] = 1.f / fmaxf(sqrtf(ss[i]), 1e-12f);
}

// ---------------- K5: attn^T via MFMA, split-K over 8 waves ----------------
__global__ __launch_bounds__(512) void k_attn(const u16* __restrict__ qkv,
                                              const float* __restrict__ rn,
                                              const float* __restrict__ temp,
                                              float* __restrict__ attn) {
    __shared__ float s_part[8][48 * 48];
    int h = blockIdx.x, b = blockIdx.y, tid = threadIdx.x;
    int wave = tid >> 6, lane = tid & 63;
    int lr = lane & 15, lk = lane >> 4;
    const u16* qp = qkv + ((size_t)b * QCH + h * 48) * NSP;
    const u16* kp = qkv + ((size_t)b * QCH + 384 + h * 48) * NSP;
    f32x4 acc[3][3];
#pragma unroll
    for (int m = 0; m < 3; m++)
#pragma unroll
        for (int n = 0; n < 3; n++) acc[m][n] = (f32x4){0.f, 0.f, 0.f, 0.f};
    int k0 = wave * 288 + lk * 8;
    short8 af[3], bf[3], afn[3], bfn[3];
#pragma unroll
    for (int m = 0; m < 3; m++) {
        af[m] = *(const short8*)(qp + (size_t)(m * 16 + lr) * NSP + k0);
        bf[m] = *(const short8*)(kp + (size_t)(m * 16 + lr) * NSP + k0);
    }
    for (int s = 0; s < 9; s++) {
        if (s < 8) {
#pragma unroll
            for (int m = 0; m < 3; m++) {
                afn[m] = *(const short8*)(qp + (size_t)(m * 16 + lr) * NSP + k0 + 32 * (s + 1));
                bfn[m] = *(const short8*)(kp + (size_t)(m * 16 + lr) * NSP + k0 + 32 * (s + 1));
            }
        }
#pragma unroll
        for (int m = 0; m < 3; m++)
#pragma unroll
            for (int n = 0; n < 3; n++)
                acc[m][n] = __builtin_amdgcn_mfma_f32_16x16x32_bf16(
                    __builtin_bit_cast(bf16x8, af[m]), __builtin_bit_cast(bf16x8, bf[n]),
                    acc[m][n], 0, 0, 0);
#pragma unroll
        for (int m = 0; m < 3; m++) { af[m] = afn[m]; bf[m] = bfn[m]; }
    }
#pragma unroll
    for (int m = 0; m < 3; m++)
#pragma unroll
        for (int n = 0; n < 3; n++)
#pragma unroll
            for (int r = 0; r < 4; r++)
                s_part[wave][(m * 16 + lk * 4 + r) * 48 + n * 16 + lr] = acc[m][n][r];
    __syncthreads();
    float th = temp[h];
    const float* rq = rn + b * 768 + h * 48;
    const float* rk = rn + b * 768 + 384 + h * 48;
    float* ap = attn + ((size_t)(b * 8 + h)) * NSP;
    for (int f = tid; f < 2304; f += 512) {
        int c = f / 48, d = f % 48;
        float v = 0.f;
#pragma unroll
        for (int wv = 0; wv < 8; wv++) v += s_part[wv][f];
        v *= th * rq[c] * rk[d];
        ap[d * 48 + c] = fmaxf(v, 0.f);   // [d][c]
    }
}

// ---------------- K6: high-pass depthwise (3/5/7), row-per-thread, register form ----------
template<int KS, int CH0, int NCH>
__global__ __launch_bounds__(256) void k_hp_t(const u16* __restrict__ qkv,
                                              const float* __restrict__ wk,
                                              const float* __restrict__ bk,
                                              u16* __restrict__ hp) {
    constexpr int PAD = KS / 2;
    constexpr int NIN = 8 + 2 * PAD;
    int t = blockIdx.x * 256 + threadIdx.x;
    int y = t % 48;
    int rem = t / 48;
    int chl = rem % NCH;
    int b = rem / NCH;
    int ch = CH0 + chl;
    const u16* src = qkv + ((size_t)b * QCH + 768 + ch) * NSP;
    float bias = bk[chl];
    float acc[48];
#pragma unroll
    for (int i = 0; i < 48; i++) acc[i] = bias;
    for (int dy = 0; dy < KS; dy++) {
        int yy = y - PAD + dy;
        if (yy < 0 || yy >= 48) continue;
        ush8 r[6];
#pragma unroll
        for (int o = 0; o < 6; o++) r[o] = *(const ush8*)(src + yy * 48 + o * 8);
        float wr[KS];
#pragma unroll
        for (int dx = 0; dx < KS; dx++) wr[dx] = wk[chl * KS * KS + dy * KS + dx];
#pragma unroll
        for (int g = 0; g < 6; g++) {
            float a[NIN];
#pragma unroll
            for (int j = 0; j < NIN; j++) {
                int xi = g * 8 - PAD + j;
                a[j] = (xi < 0 || xi >= 48) ? 0.f : b2f(r[xi >> 3][xi & 7]);
            }
#pragma unroll
            for (int x = 0; x < 8; x++) {
                float s = 0.f;
#pragma unroll
                for (int dx = 0; dx < KS; dx++) s += a[x + dx] * wr[dx];
                acc[g * 8 + x] += s;
            }
        }
    }
    u16* dst = hp + ((size_t)b * CDIM + ch) * NSP + y * 48;
#pragma unroll
    for (int g = 0; g < 6; g++) {
        union { u16 u[8]; short8 v; } pk;
#pragma unroll
        for (int x = 0; x < 8; x++) pk.u[x] = f2b(acc[g * 8 + x]);
        *(short8*)(dst + g * 8) = pk.v;
    }
}

// ---------------- K7: adaptive avg pool (exact jnp boundaries) ----------------
__global__ __launch_bounds__(64) void k_pool(const u16* __restrict__ qkv,
                                             float* __restrict__ pooled) {
    int c = blockIdx.x, b = blockIdx.y, tid = threadIdx.x;
    int s = 2 * (c / 96) + 1;  // 1,3,5,7
    __shared__ float rp[48][7];
    const u16* src = qkv + ((size_t)b * QCH + 768 + c) * NSP;
    if (tid < 48) {
        for (int q = 0; q < s; q++) {
            int a = q * 48 / s, e = ((q + 1) * 48 + s - 1) / s;
            float sum = 0.f;
            for (int xx = a; xx < e; xx++) sum += b2f(src[tid * 48 + xx]);
            rp[tid][q] = sum / (float)(e - a);
        }
    }
    __syncthreads();
    if (tid < s * s) {
        int p = tid / s, q = tid % s;
        int a = p * 48 / s, e = ((p + 1) * 48 + s - 1) / s;
        float sum = 0.f;
        for (int r = a; r < e; r++) sum += rp[r][q];
        pooled[((size_t)b * CDIM + c) * 49 + tid] = sum / (float)(e - a);
    }
}

// ---------------- K8: out = 1/sqrt(48)*attn@v + qn*HP + LP, col-per-thread ----------
__global__ __launch_bounds__(256, 4) void k_out(const u16* __restrict__ qkv,
                                                const float* __restrict__ attnT,
                                                const float* __restrict__ rn,
                                                const u16* __restrict__ hp,
                                                const float* __restrict__ pooled,
                                                u16* __restrict__ tmpt) {
    int nc = blockIdx.x, h = blockIdx.y, b = blockIdx.z, tid = threadIdx.x;
    __shared__ float s_at[48 * 48];   // [d][c]
    __shared__ float s_rq[48];
    __shared__ float s_pool[48][49];
    for (int f = tid; f < 48 * 48; f += 256) s_at[f] = attnT[((size_t)(b * 8 + h)) * NSP + f];
    if (tid < 48) s_rq[tid] = rn[b * 768 + h * 48 + tid];
    for (int f = tid; f < 48 * 49; f += 256)
        s_pool[f / 49][f % 49] = pooled[((size_t)b * CDIM + h * 48) * 49 + f];
    __syncthreads();
    int s = 2 * (h / 2) + 1;
    int n = nc * 256 + tid;
    const u16* vp = qkv + ((size_t)b * QCH + 768 + h * 48) * NSP + n;
    const u16* qp = qkv + ((size_t)b * QCH + h * 48) * NSP + n;
    const u16* hq = hp + ((size_t)b * CDIM + h * 48) * NSP + n;
    float acc[48];
#pragma unroll
    for (int c = 0; c < 48; c++) acc[c] = 0.f;
    for (int d = 0; d < 48; d++) {
        float vd = b2f(vp[(size_t)d * NSP]);
        const float* at = &s_at[d * 48];
#pragma unroll
        for (int c = 0; c < 48; c++) acc[c] += at[c] * vd;
    }
    const float inv = 0.14433756729740643f;  // 48^-0.5
    int y = n / 48, xx = n % 48;
    float syf = (y + 0.5f) * s * (1.f / 48.f) - 0.5f;
    int iy0 = (int)floorf(syf); float fy = syf - (float)iy0;
    int iy1 = min(iy0 + 1, s - 1); iy0 = max(iy0, 0);
    float sxf = (xx + 0.5f) * s * (1.f / 48.f) - 0.5f;
    int ix0 = (int)floorf(sxf); float fx = sxf - (float)ix0;
    int ix1 = min(ix0 + 1, s - 1); ix0 = max(ix0, 0);
    u16* tp = tmpt + ((size_t)b * NSP + n) * CDIM + h * 48;
#pragma unroll
    for (int c8 = 0; c8 < 6; c8++) {
        union { u16 u[8]; short8 v; } pk;
#pragma unroll
        for (int cc = 0; cc < 8; cc++) {
            int ch = c8 * 8 + cc;
            float qv = b2f(qp[(size_t)ch * NSP]);
            float hv = b2f(hq[(size_t)ch * NSP]);
            const float* P = s_pool[ch];
            float lp = (1.f - fy) * ((1.f - fx) * P[iy0 * s + ix0] + fx * P[iy0 * s + ix1])
                     + fy * ((1.f - fx) * P[iy1 * s + ix0] + fx * P[iy1 * s + ix1]);
            lp = fmaxf(lp, 0.f);
            float val = inv * acc[ch] + qv * s_rq[ch] * hv + lp;
            pk.u[cc] = f2b(val);
        }
        *(short8*)(tp + c8 * 8) = pk.v;
    }
}

extern "C" void kernel_launch(void* const* d_in, const int* in_sizes, int n_in,
                              void* d_out, int out_size, void* d_ws, size_t ws_size,
                              hipStream_t stream) {
    const float* x    = (const float*)d_in[0];
    const float* lnw  = (const float*)d_in[1];
    const float* lnb  = (const float*)d_in[2];
    const float* wqkv = (const float*)d_in[3];
    const float* wdw  = (const float*)d_in[4];
    const float* temp = (const float*)d_in[5];
    const float* w3   = (const float*)d_in[6];
    const float* b3   = (const float*)d_in[7];
    const float* w5   = (const float*)d_in[8];
    const float* b5   = (const float*)d_in[9];
    const float* w7   = (const float*)d_in[10];
    const float* b7   = (const float*)d_in[11];
    const float* wproj= (const float*)d_in[12];
    float* out = (float*)d_out;

    char* w = (char*)d_ws;
    const size_t SZ_XNT = (size_t)NB * NSP * CDIM * 2;   // 56,623,104  (xn; reused as tmpt)
    const size_t SZ_QKV = (size_t)NB * QCH * NSP * 2;    // 169,869,312
    u16* xnt      = (u16*)w;
    u16* qkv_raw  = (u16*)(w + SZ_XNT);                  // gemm out; hp reuses this after dw3
    u16* qkv_conv = (u16*)(w + SZ_XNT + SZ_QKV);         // dw3 out (new)
    char* tail    = w + SZ_XNT + 2 * SZ_QKV;
    float* sumsq  = (float*)tail;
    float* rnorm  = sumsq + NB * 768;
    float* attnb  = rnorm + NB * 768;
    float* pooled = attnb + (size_t)NB * 8 * NSP;
    u16* wqkv_bf  = (u16*)(pooled + (size_t)NB * CDIM * 49);
    u16* wproj_bf = wqkv_bf + (size_t)QCH * CDIM;
    u16* hpb  = qkv_raw;   // dead after dw3; 56.6 MB needed of 170 available
    u16* tmpt = xnt;

    k_prep <<<dim3((QCH * CDIM + 255) / 256), 256, 0, stream>>>(wqkv, wproj, wqkv_bf, wproj_bf);
    k_ln   <<<dim3(36, NB), 256, 0, stream>>>(x, lnw, lnb, xnt);
    k_gemm <<<dim3(18, 9, NB), 256, 0, stream>>>(wqkv_bf, xnt, qkv_raw, QCH, 0);
    k_dw3  <<<dim3(288, NB), 192, 0, stream>>>(qkv_raw, qkv_conv, wdw, sumsq);
    k_rnorm<<<dim3(96), 256, 0, stream>>>(sumsq, rnorm);
    k_attn <<<dim3(8, NB), 512, 0, stream>>>(qkv_conv, rnorm, temp, attnb);
    k_hp_t<3, 0, 144>   <<<dim3(864), 256, 0, stream>>>(qkv_conv, w3, b3, hpb);
    k_hp_t<5, 144, 144> <<<dim3(864), 256, 0, stream>>>(qkv_conv, w5, b5, hpb);
    k_hp_t<7, 288, 96>  <<<dim3(576), 256, 0, stream>>>(qkv_conv, w7, b7, hpb);
    k_pool <<<dim3(CDIM, NB), 64, 0, stream>>>(qkv_conv, pooled);
    k_out  <<<dim3(9, 8, NB), 256, 0, stream>>>(qkv_conv, attnb, rnorm, hpb, pooled, tmpt);
    k_gemm <<<dim3(18, 3, NB), 256, 0, stream>>>(wproj_bf, tmpt, out, CDIM, 1);
}

// Round 9
// 571.779 us; speedup vs baseline: 1.0945x; 1.0945x over previous
//
#include <hip/hip_runtime.h>

typedef unsigned short u16;
typedef short short8 __attribute__((ext_vector_type(8)));
typedef u16 ush8 __attribute__((ext_vector_type(8)));
typedef __bf16 bf16x8 __attribute__((ext_vector_type(8)));
typedef float f32x4 __attribute__((ext_vector_type(4)));

#define NB 32
#define CDIM 384
#define NSP 2304
#define QCH 1152

__device__ __forceinline__ float b2f(u16 u) {
    union { unsigned i; float f; } v; v.i = ((unsigned)u) << 16; return v.f;
}
__device__ __forceinline__ u16 f2b(float f) {
    union { float f; unsigned i; } v; v.f = f;
    unsigned r = v.i + 0x7FFFu + ((v.i >> 16) & 1u);
    return (u16)(r >> 16);
}

// ---------------- K0: convert f32 weights to bf16 ----------
__global__ __launch_bounds__(256) void k_prep(const float* __restrict__ wqkv,
                                              const float* __restrict__ wproj,
                                              u16* __restrict__ wqkv_bf,
                                              u16* __restrict__ wproj_bf) {
    int i = blockIdx.x * 256 + threadIdx.x;
    if (i < QCH * CDIM) wqkv_bf[i] = f2b(wqkv[i]);
    if (i < CDIM * CDIM) wproj_bf[i] = f2b(wproj[i]);
}

// ---------------- K1: channel LayerNorm, single-pass register-resident, vectorized out ------
__global__ __launch_bounds__(256) void k_ln(const float* __restrict__ x,
                                            const float* __restrict__ lnw,
                                            const float* __restrict__ lnb,
                                            u16* __restrict__ xnt) {
    __shared__ float s_sum[4][64], s_sq[4][64], s_mu[64], s_rs[64];
    __shared__ u16 s_tile[64][392];   // 784B row stride: 16B aligned
    int b = blockIdx.y, n0 = blockIdx.x * 64;
    int tid = threadIdx.x, c4 = tid >> 6, nl = tid & 63;
    int cbase = c4 * 96;
    const float* xb = x + (size_t)b * CDIM * NSP + (size_t)cbase * NSP + n0 + nl;
    float v[96];
    float sum = 0.f, sq = 0.f;
#pragma unroll
    for (int j = 0; j < 96; j++) {
        v[j] = xb[(size_t)j * NSP];
        sum += v[j]; sq += v[j] * v[j];
    }
    s_sum[c4][nl] = sum; s_sq[c4][nl] = sq;
    __syncthreads();
    if (tid < 64) {
        float s = s_sum[0][tid] + s_sum[1][tid] + s_sum[2][tid] + s_sum[3][tid];
        float q = s_sq[0][tid] + s_sq[1][tid] + s_sq[2][tid] + s_sq[3][tid];
        float mu = s * (1.f / CDIM);
        float var = q * (1.f / CDIM) - mu * mu;
        s_mu[tid] = mu; s_rs[tid] = rsqrtf(var + 1e-5f);
    }
    __syncthreads();
    float mu = s_mu[nl], rs = s_rs[nl];
#pragma unroll
    for (int j = 0; j < 96; j++) {
        int c = cbase + j;
        s_tile[nl][c] = f2b((v[j] - mu) * rs * lnw[c] + lnb[c]);
    }
    __syncthreads();
    u16* o = xnt + ((size_t)b * NSP + n0) * CDIM;
    for (int i = tid; i < 64 * 48; i += 256) {
        int row = i / 48, c8 = i % 48;
        *(short8*)(o + row * CDIM + c8 * 8) = *(const short8*)(&s_tile[row][c8 * 8]);
    }
}

// ---------------- K2/K9: GEMM  C[b][m][n] = sum_k A[m][k] * Bt[b][n][k] ----------------
__global__ __launch_bounds__(256) void k_gemm(const u16* __restrict__ A,
                                              const u16* __restrict__ Bt,
                                              void* __restrict__ Cmat, int M, int f32out) {
    __shared__ u16 As[128][40], Bs[128][40];
    int tid = threadIdx.x;
    int bxn = blockIdx.x, bym = blockIdx.y, bz = blockIdx.z;
    int wave = tid >> 6, lane = tid & 63, wr = wave >> 1, wc = wave & 1;
    int lr = lane & 15, lk = lane >> 4;
    f32x4 acc[4][4];
#pragma unroll
    for (int m = 0; m < 4; m++)
#pragma unroll
        for (int n = 0; n < 4; n++) acc[m][n] = (f32x4){0.f, 0.f, 0.f, 0.f};
    int rs = tid >> 2, ks = (tid & 3) * 8;
    const u16* Ap0 = A + (size_t)(bym * 128 + rs) * 384 + ks;
    const u16* Ap1 = Ap0 + (size_t)64 * 384;
    const u16* Bp0 = Bt + ((size_t)bz * NSP + bxn * 128 + rs) * 384 + ks;
    const u16* Bp1 = Bp0 + (size_t)64 * 384;
    for (int k0 = 0; k0 < 384; k0 += 32) {
        *(short8*)(&As[rs][ks])      = *(const short8*)(Ap0 + k0);
        *(short8*)(&As[rs + 64][ks]) = *(const short8*)(Ap1 + k0);
        *(short8*)(&Bs[rs][ks])      = *(const short8*)(Bp0 + k0);
        *(short8*)(&Bs[rs + 64][ks]) = *(const short8*)(Bp1 + k0);
        __syncthreads();
        short8 af[4], bfr[4];
#pragma unroll
        for (int m = 0; m < 4; m++) af[m] = *(const short8*)(&As[wr * 64 + m * 16 + lr][lk * 8]);
#pragma unroll
        for (int n = 0; n < 4; n++) bfr[n] = *(const short8*)(&Bs[wc * 64 + n * 16 + lr][lk * 8]);
#pragma unroll
        for (int m = 0; m < 4; m++)
#pragma unroll
            for (int n = 0; n < 4; n++)
                acc[m][n] = __builtin_amdgcn_mfma_f32_16x16x32_bf16(
                    __builtin_bit_cast(bf16x8, af[m]), __builtin_bit_cast(bf16x8, bfr[n]),
                    acc[m][n], 0, 0, 0);
        __syncthreads();
    }
#pragma unroll
    for (int m = 0; m < 4; m++)
#pragma unroll
        for (int n = 0; n < 4; n++) {
            int row = bym * 128 + wr * 64 + m * 16 + lk * 4;
            int col = bxn * 128 + wc * 64 + n * 16 + lr;
            if (f32out) {
                float* cp = (float*)Cmat + ((size_t)bz * M + row) * NSP + col;
#pragma unroll
                for (int r = 0; r < 4; r++) cp[(size_t)r * NSP] = acc[m][n][r];
            } else {
                u16* cp = (u16*)Cmat + ((size_t)bz * M + row) * NSP + col;
#pragma unroll
                for (int r = 0; r < 4; r++) cp[(size_t)r * NSP] = f2b(acc[m][n][r]);
            }
        }
}

// ---------------- K3 v3: 3x3 depthwise IN-PLACE, LDS-bounced coalesced I/O ----------------
// Block: 192 threads / 4 contiguous planes (18.4KB linear in both LDS and global).
// Stage-in coalesced -> barrier (covers in-place safety) -> register conv from LDS ->
// barrier -> outputs to LDS -> barrier -> coalesced stage-out in place.
__global__ __launch_bounds__(192) void k_dw3(u16* __restrict__ qkv,
                                             const float* __restrict__ wdw,
                                             float* __restrict__ sumsq) {
    __shared__ u16 s_in[4 * 2304];
    __shared__ float s_part[192];
    int bx = blockIdx.x, b = blockIdx.y, tid = threadIdx.x;
    u16* gbase = qkv + ((size_t)b * QCH + bx * 4) * NSP;
#pragma unroll
    for (int i = 0; i < 6; i++) {
        int c = tid + i * 192;
        *(ush8*)(&s_in[c * 8]) = *(const ush8*)(gbase + c * 8);
    }
    int p = tid / 48, y = tid % 48;
    int ch = bx * 4 + p;
    float w[9];
#pragma unroll
    for (int i = 0; i < 9; i++) w[i] = wdw[ch * 9 + i];
    __syncthreads();
    const u16* L = &s_in[p * 2304];
    ush8 r0[6], r1[6], r2[6];
#pragma unroll
    for (int o = 0; o < 6; o++) {
        r1[o] = *(const ush8*)(L + y * 48 + o * 8);
        if (y > 0)  r0[o] = *(const ush8*)(L + (y - 1) * 48 + o * 8); else r0[o] = 0;
        if (y < 47) r2[o] = *(const ush8*)(L + (y + 1) * 48 + o * 8); else r2[o] = 0;
    }
    float ss = 0.f;
    short8 outv[6];
#pragma unroll
    for (int g = 0; g < 6; g++) {
        float a0[10], a1[10], a2[10];
#pragma unroll
        for (int j = 0; j < 10; j++) {
            int xi = g * 8 - 1 + j;
            if (xi < 0 || xi >= 48) { a0[j] = 0.f; a1[j] = 0.f; a2[j] = 0.f; }
            else {
                a0[j] = b2f(r0[xi >> 3][xi & 7]);
                a1[j] = b2f(r1[xi >> 3][xi & 7]);
                a2[j] = b2f(r2[xi >> 3][xi & 7]);
            }
        }
        union { u16 u[8]; short8 v; } pk;
#pragma unroll
        for (int x = 0; x < 8; x++) {
            float o = a0[x] * w[0] + a0[x + 1] * w[1] + a0[x + 2] * w[2]
                    + a1[x] * w[3] + a1[x + 1] * w[4] + a1[x + 2] * w[5]
                    + a2[x] * w[6] + a2[x + 1] * w[7] + a2[x + 2] * w[8];
            ss += o * o;
            pk.u[x] = f2b(o);
        }
        outv[g] = pk.v;
    }
    s_part[tid] = ss;
    __syncthreads();   // all LDS reads done; safe to overwrite
#pragma unroll
    for (int g = 0; g < 6; g++)
        *(short8*)(&s_in[p * 2304 + y * 48 + g * 8]) = outv[g];
    __syncthreads();
#pragma unroll
    for (int i = 0; i < 6; i++) {
        int c = tid + i * 192;
        *(ush8*)(gbase + c * 8) = *(const ush8*)(&s_in[c * 8]);
    }
    if (bx < 192 && tid < 4) {
        float s = 0.f;
        for (int i = 0; i < 48; i++) s += s_part[tid * 48 + i];
        sumsq[b * 768 + bx * 4 + tid] = s;
    }
}

// ---------------- K4: 1/max(sqrt(ss),1e-12) ----------------
__global__ void k_rnorm(const float* __restrict__ ss, float* __restrict__ rn) {
    int i = blockIdx.x * 256 + threadIdx.x;
    if (i < NB * 768) rn[i] = 1.f / fmaxf(sqrtf(ss[i]), 1e-12f);
}

// ---------------- K5: attn^T via MFMA, split-K over 8 waves ----------------
__global__ __launch_bounds__(512) void k_attn(const u16* __restrict__ qkv,
                                              const float* __restrict__ rn,
                                              const float* __restrict__ temp,
                                              float* __restrict__ attn) {
    __shared__ float s_part[8][48 * 48];
    int h = blockIdx.x, b = blockIdx.y, tid = threadIdx.x;
    int wave = tid >> 6, lane = tid & 63;
    int lr = lane & 15, lk = lane >> 4;
    const u16* qp = qkv + ((size_t)b * QCH + h * 48) * NSP;
    const u16* kp = qkv + ((size_t)b * QCH + 384 + h * 48) * NSP;
    f32x4 acc[3][3];
#pragma unroll
    for (int m = 0; m < 3; m++)
#pragma unroll
        for (int n = 0; n < 3; n++) acc[m][n] = (f32x4){0.f, 0.f, 0.f, 0.f};
    int k0 = wave * 288 + lk * 8;
    short8 af[3], bf[3], afn[3], bfn[3];
#pragma unroll
    for (int m = 0; m < 3; m++) {
        af[m] = *(const short8*)(qp + (size_t)(m * 16 + lr) * NSP + k0);
        bf[m] = *(const short8*)(kp + (size_t)(m * 16 + lr) * NSP + k0);
    }
    for (int s = 0; s < 9; s++) {
        if (s < 8) {
#pragma unroll
            for (int m = 0; m < 3; m++) {
                afn[m] = *(const short8*)(qp + (size_t)(m * 16 + lr) * NSP + k0 + 32 * (s + 1));
                bfn[m] = *(const short8*)(kp + (size_t)(m * 16 + lr) * NSP + k0 + 32 * (s + 1));
            }
        }
#pragma unroll
        for (int m = 0; m < 3; m++)
#pragma unroll
            for (int n = 0; n < 3; n++)
                acc[m][n] = __builtin_amdgcn_mfma_f32_16x16x32_bf16(
                    __builtin_bit_cast(bf16x8, af[m]), __builtin_bit_cast(bf16x8, bf[n]),
                    acc[m][n], 0, 0, 0);
#pragma unroll
        for (int m = 0; m < 3; m++) { af[m] = afn[m]; bf[m] = bfn[m]; }
    }
#pragma unroll
    for (int m = 0; m < 3; m++)
#pragma unroll
        for (int n = 0; n < 3; n++)
#pragma unroll
            for (int r = 0; r < 4; r++)
                s_part[wave][(m * 16 + lk * 4 + r) * 48 + n * 16 + lr] = acc[m][n][r];
    __syncthreads();
    float th = temp[h];
    const float* rq = rn + b * 768 + h * 48;
    const float* rk = rn + b * 768 + 384 + h * 48;
    float* ap = attn + ((size_t)(b * 8 + h)) * NSP;
    for (int f = tid; f < 2304; f += 512) {
        int c = f / 48, d = f % 48;
        float v = 0.f;
#pragma unroll
        for (int wv = 0; wv < 8; wv++) v += s_part[wv][f];
        v *= th * rq[c] * rk[d];
        ap[d * 48 + c] = fmaxf(v, 0.f);   // [d][c]
    }
}

// ---------------- K6: high-pass depthwise (3/5/7), row-per-thread, register form ----------
template<int KS, int CH0, int NCH>
__global__ __launch_bounds__(256) void k_hp_t(const u16* __restrict__ qkv,
                                              const float* __restrict__ wk,
                                              const float* __restrict__ bk,
                                              u16* __restrict__ hp) {
    constexpr int PAD = KS / 2;
    constexpr int NIN = 8 + 2 * PAD;
    int t = blockIdx.x * 256 + threadIdx.x;
    int y = t % 48;
    int rem = t / 48;
    int chl = rem % NCH;
    int b = rem / NCH;
    int ch = CH0 + chl;
    const u16* src = qkv + ((size_t)b * QCH + 768 + ch) * NSP;
    float bias = bk[chl];
    float acc[48];
#pragma unroll
    for (int i = 0; i < 48; i++) acc[i] = bias;
    for (int dy = 0; dy < KS; dy++) {
        int yy = y - PAD + dy;
        if (yy < 0 || yy >= 48) continue;
        ush8 r[6];
#pragma unroll
        for (int o = 0; o < 6; o++) r[o] = *(const ush8*)(src + yy * 48 + o * 8);
        float wr[KS];
#pragma unroll
        for (int dx = 0; dx < KS; dx++) wr[dx] = wk[chl * KS * KS + dy * KS + dx];
#pragma unroll
        for (int g = 0; g < 6; g++) {
            float a[NIN];
#pragma unroll
            for (int j = 0; j < NIN; j++) {
                int xi = g * 8 - PAD + j;
                a[j] = (xi < 0 || xi >= 48) ? 0.f : b2f(r[xi >> 3][xi & 7]);
            }
#pragma unroll
            for (int x = 0; x < 8; x++) {
                float s = 0.f;
#pragma unroll
                for (int dx = 0; dx < KS; dx++) s += a[x + dx] * wr[dx];
                acc[g * 8 + x] += s;
            }
        }
    }
    u16* dst = hp + ((size_t)b * CDIM + ch) * NSP + y * 48;
#pragma unroll
    for (int g = 0; g < 6; g++) {
        union { u16 u[8]; short8 v; } pk;
#pragma unroll
        for (int x = 0; x < 8; x++) pk.u[x] = f2b(acc[g * 8 + x]);
        *(short8*)(dst + g * 8) = pk.v;
    }
}

// ---------------- K7: adaptive avg pool (exact jnp boundaries) ----------------
__global__ __launch_bounds__(64) void k_pool(const u16* __restrict__ qkv,
                                             float* __restrict__ pooled) {
    int c = blockIdx.x, b = blockIdx.y, tid = threadIdx.x;
    int s = 2 * (c / 96) + 1;  // 1,3,5,7
    __shared__ float rp[48][7];
    const u16* src = qkv + ((size_t)b * QCH + 768 + c) * NSP;
    if (tid < 48) {
        for (int q = 0; q < s; q++) {
            int a = q * 48 / s, e = ((q + 1) * 48 + s - 1) / s;
            float sum = 0.f;
            for (int xx = a; xx < e; xx++) sum += b2f(src[tid * 48 + xx]);
            rp[tid][q] = sum / (float)(e - a);
        }
    }
    __syncthreads();
    if (tid < s * s) {
        int p = tid / s, q = tid % s;
        int a = p * 48 / s, e = ((p + 1) * 48 + s - 1) / s;
        float sum = 0.f;
        for (int r = a; r < e; r++) sum += rp[r][q];
        pooled[((size_t)b * CDIM + c) * 49 + tid] = sum / (float)(e - a);
    }
}

// ---------------- K8: out = 1/sqrt(48)*attn@v + qn*HP + LP, col-per-thread ----------
__global__ __launch_bounds__(256, 4) void k_out(const u16* __restrict__ qkv,
                                                const float* __restrict__ attnT,
                                                const float* __restrict__ rn,
                                                const u16* __restrict__ hp,
                                                const float* __restrict__ pooled,
                                                u16* __restrict__ tmpt) {
    int nc = blockIdx.x, h = blockIdx.y, b = blockIdx.z, tid = threadIdx.x;
    __shared__ float s_at[48 * 48];   // [d][c]
    __shared__ float s_rq[48];
    __shared__ float s_pool[48][49];
    for (int f = tid; f < 48 * 48; f += 256) s_at[f] = attnT[((size_t)(b * 8 + h)) * NSP + f];
    if (tid < 48) s_rq[tid] = rn[b * 768 + h * 48 + tid];
    for (int f = tid; f < 48 * 49; f += 256)
        s_pool[f / 49][f % 49] = pooled[((size_t)b * CDIM + h * 48) * 49 + f];
    __syncthreads();
    int s = 2 * (h / 2) + 1;
    int n = nc * 256 + tid;
    const u16* vp = qkv + ((size_t)b * QCH + 768 + h * 48) * NSP + n;
    const u16* qp = qkv + ((size_t)b * QCH + h * 48) * NSP + n;
    const u16* hq = hp + ((size_t)b * CDIM + h * 48) * NSP + n;
    float acc[48];
#pragma unroll
    for (int c = 0; c < 48; c++) acc[c] = 0.f;
    for (int d = 0; d < 48; d++) {
        float vd = b2f(vp[(size_t)d * NSP]);
        const float* at = &s_at[d * 48];
#pragma unroll
        for (int c = 0; c < 48; c++) acc[c] += at[c] * vd;
    }
    const float inv = 0.14433756729740643f;  // 48^-0.5
    int y = n / 48, xx = n % 48;
    float syf = (y + 0.5f) * s * (1.f / 48.f) - 0.5f;
    int iy0 = (int)floorf(syf); float fy = syf - (float)iy0;
    int iy1 = min(iy0 + 1, s - 1); iy0 = max(iy0, 0);
    float sxf = (xx + 0.5f) * s * (1.f / 48.f) - 0.5f;
    int ix0 = (int)floorf(sxf); float fx = sxf - (float)ix0;
    int ix1 = min(ix0 + 1, s - 1); ix0 = max(ix0, 0);
    u16* tp = tmpt + ((size_t)b * NSP + n) * CDIM + h * 48;
#pragma unroll
    for (int c8 = 0; c8 < 6; c8++) {
        union { u16 u[8]; short8 v; } pk;
#pragma unroll
        for (int cc = 0; cc < 8; cc++) {
            int ch = c8 * 8 + cc;
            float qv = b2f(qp[(size_t)ch * NSP]);
            float hv = b2f(hq[(size_t)ch * NSP]);
            const float* P = s_pool[ch];
            float lp = (1.f - fy) * ((1.f - fx) * P[iy0 * s + ix0] + fx * P[iy0 * s + ix1])
                     + fy * ((1.f - fx) * P[iy1 * s + ix0] + fx * P[iy1 * s + ix1]);
            lp = fmaxf(lp, 0.f);
            float val = inv * acc[ch] + qv * s_rq[ch] * hv + lp;
            pk.u[cc] = f2b(val);
        }
        *(short8*)(tp + c8 * 8) = pk.v;
    }
}

extern "C" void kernel_launch(void* const* d_in, const int* in_sizes, int n_in,
                              void* d_out, int out_size, void* d_ws, size_t ws_size,
                              hipStream_t stream) {
    const float* x    = (const float*)d_in[0];
    const float* lnw  = (const float*)d_in[1];
    const float* lnb  = (const float*)d_in[2];
    const float* wqkv = (const float*)d_in[3];
    const float* wdw  = (const float*)d_in[4];
    const float* temp = (const float*)d_in[5];
    const float* w3   = (const float*)d_in[6];
    const float* b3   = (const float*)d_in[7];
    const float* w5   = (const float*)d_in[8];
    const float* b5   = (const float*)d_in[9];
    const float* w7   = (const float*)d_in[10];
    const float* b7   = (const float*)d_in[11];
    const float* wproj= (const float*)d_in[12];
    float* out = (float*)d_out;

    char* w = (char*)d_ws;
    const size_t SZ_XNT = (size_t)NB * NSP * CDIM * 2;   // 56,623,104  (xn; reused as tmpt)
    const size_t SZ_QKV = (size_t)NB * QCH * NSP * 2;    // 169,869,312
    u16* xnt      = (u16*)w;
    u16* qkvb     = (u16*)(w + SZ_XNT);                  // gemm out; dw3 in-place
    u16* hpb      = (u16*)(w + SZ_XNT + SZ_QKV);         // hp output
    char* tail    = w + SZ_XNT + SZ_QKV + (size_t)NB * CDIM * NSP * 2;
    float* sumsq  = (float*)tail;
    float* rnorm  = sumsq + NB * 768;
    float* attnb  = rnorm + NB * 768;
    float* pooled = attnb + (size_t)NB * 8 * NSP;
    u16* wqkv_bf  = (u16*)(pooled + (size_t)NB * CDIM * 49);
    u16* wproj_bf = wqkv_bf + (size_t)QCH * CDIM;
    u16* tmpt = xnt;

    k_prep <<<dim3((QCH * CDIM + 255) / 256), 256, 0, stream>>>(wqkv, wproj, wqkv_bf, wproj_bf);
    k_ln   <<<dim3(36, NB), 256, 0, stream>>>(x, lnw, lnb, xnt);
    k_gemm <<<dim3(18, 9, NB), 256, 0, stream>>>(wqkv_bf, xnt, qkvb, QCH, 0);
    k_dw3  <<<dim3(288, NB), 192, 0, stream>>>(qkvb, wdw, sumsq);
    k_rnorm<<<dim3(96), 256, 0, stream>>>(sumsq, rnorm);
    k_attn <<<dim3(8, NB), 512, 0, stream>>>(qkvb, rnorm, temp, attnb);
    k_hp_t<3, 0, 144>   <<<dim3(864), 256, 0, stream>>>(qkvb, w3, b3, hpb);
    k_hp_t<5, 144, 144> <<<dim3(864), 256, 0, stream>>>(qkvb, w5, b5, hpb);
    k_hp_t<7, 288, 96>  <<<dim3(576), 256, 0, stream>>>(qkvb, w7, b7, hpb);
    k_pool <<<dim3(CDIM, NB), 64, 0, stream>>>(qkvb, pooled);
    k_out  <<<dim3(9, 8, NB), 256, 0, stream>>>(qkvb, attnb, rnorm, hpb, pooled, tmpt);
    k_gemm <<<dim3(18, 3, NB), 256, 0, stream>>>(wproj_bf, tmpt, out, CDIM, 1);
}